// Round 1
// baseline (2890.916 us; speedup 1.0000x reference)
//
#include <hip/hip_runtime.h>

#define BATCH 16
#define NBOX  2048
#define NCLS  80
#define ROWF  85          // 4 box + 1 score + 80 classprobs
#define CONF_THRF 0.2f
#define NMS_THRF  0.45f
#define CAP   128         // max kept per (image,class); stats say ~25, 128 is very safe

// ---------------- kernel 1: per-box score / classprob max / argmax ----------------
__global__ __launch_bounds__(256) void prep_kernel(const float* __restrict__ det,
                                                   float* __restrict__ s_ws,
                                                   float* __restrict__ cp_ws,
                                                   int* __restrict__ l_ws) {
  int g = blockIdx.x * blockDim.x + threadIdx.x;
  if (g >= BATCH * NBOX) return;
  const float* r = det + (size_t)g * ROWF;
  float sc = r[4];
  float best = r[5];
  int bi = 0;
#pragma unroll
  for (int c = 1; c < NCLS; ++c) {
    float v = r[5 + c];
    if (v > best) { best = v; bi = c; }   // strict > keeps FIRST max (argmax semantics)
  }
  s_ws[g] = sc;
  cp_ws[g] = best;
  l_ws[g] = bi;
}

// ---------------- kernel 2: per-image sort + class-separable greedy NMS + compact ----------------
__global__ __launch_bounds__(1024) void nms_kernel(const float* __restrict__ det,
                                                   const float* __restrict__ s_ws,
                                                   const float* __restrict__ cp_ws,
                                                   const int* __restrict__ l_ws,
                                                   float* __restrict__ out,
                                                   float* __restrict__ olb,
                                                   float* __restrict__ omask) {
  __shared__ unsigned long long key[NBOX];          // 16 KB
  __shared__ float bx1[NBOX], by1[NBOX], bx2[NBOX], by2[NBOX];  // 32 KB (offset boxes, sorted order)
  __shared__ unsigned short clist[NCLS][CAP];       // 20 KB kept positions per class
  __shared__ unsigned char keepf[NBOX];             // 2 KB
  __shared__ int pexc[NBOX];                        // 8 KB exclusive prefix of keep
  __shared__ unsigned short plist[NBOX];            // 4 KB rank -> sorted position
  __shared__ int wsum[16], wscan[16];
  __shared__ int Ktot;

  const int img = blockIdx.x;
  const int tid = threadIdx.x;
  const size_t ibase = (size_t)img * NBOX;

  // ---- build sort keys: (~score_bits)<<32 | (idx<<7 | label); non-candidates -> hi=0xFFFFFFFF
  // ascending 64-bit sort == stable (score desc, idx asc), non-candidates last in idx order,
  // exactly matching jnp stable argsort of -where(cand, s, -inf).
  for (int i = tid; i < NBOX; i += 1024) {
    float sc = s_ws[ibase + i];
    int lb = l_ws[ibase + i];
    unsigned sb = __float_as_uint(sc);            // sc in [0,1): bits monotone with value
    unsigned hi = (sc > CONF_THRF) ? ~sb : 0xFFFFFFFFu;
    key[i] = ((unsigned long long)hi << 32) | (unsigned)((i << 7) | lb);
    keepf[i] = 0;
  }
  __syncthreads();

  // ---- bitonic sort ascending, 2048 elems, 1024 threads = 1 pair/thread/pass
  for (int k = 2; k <= NBOX; k <<= 1) {
    for (int j = k >> 1; j > 0; j >>= 1) {
      int i = ((tid & ~(j - 1)) << 1) | (tid & (j - 1));
      int ixj = i + j;
      unsigned long long a = key[i], b = key[ixj];
      bool up = ((i & k) == 0);
      if (up ? (a > b) : (a < b)) { key[i] = b; key[ixj] = a; }
      __syncthreads();
    }
  }

  // ---- gather offset boxes (b + label*10000, f32, same rounding as reference) in sorted order
  for (int i = tid; i < NBOX; i += 1024) {
    unsigned meta = (unsigned)key[i];
    int orig = (meta >> 7) & (NBOX - 1);
    int lb = meta & 127;
    const float* rr = det + (ibase + orig) * ROWF;
    float off = (float)lb * 10000.0f;
    bx1[i] = rr[0] + off;
    by1[i] = rr[1] + off;
    bx2[i] = rr[2] + off;
    by2[i] = rr[3] + off;
  }
  __syncthreads();

  // ---- per-class greedy NMS (classes never interact: offset >= 10000 apart -> IoU == 0)
  if (tid < NCLS) {
    int c = tid, cnt = 0;
    for (int i = 0; i < NBOX; ++i) {
      unsigned long long kv = key[i];
      if ((unsigned)(kv >> 32) == 0xFFFFFFFFu) break;   // non-candidates start; none kept after
      if (((unsigned)kv & 127u) != (unsigned)c) continue;
      float x1 = bx1[i], y1 = by1[i], x2 = bx2[i], y2 = by2[i];
      float ar = fmaxf(x2 - x1, 0.0f) * fmaxf(y2 - y1, 0.0f);
      bool sup = false;
      for (int q = 0; q < cnt; ++q) {
        int p = clist[c][q];
        float px1 = bx1[p], py1 = by1[p], px2 = bx2[p], py2 = by2[p];
        float par = fmaxf(px2 - px1, 0.0f) * fmaxf(py2 - py1, 0.0f);
        float iw = fminf(x2, px2) - fmaxf(x1, px1);
        float ih = fminf(y2, py2) - fmaxf(y1, py1);
        float inter = fmaxf(iw, 0.0f) * fmaxf(ih, 0.0f);
        float iou = inter / (((par + ar) - inter) + 1e-7f);  // exact ref op order
        if (iou > NMS_THRF) { sup = true; break; }
      }
      if (!sup) {
        if (cnt < CAP) clist[c][cnt] = (unsigned short)i;
        cnt++;
        keepf[i] = 1;
      }
    }
  }
  __syncthreads();

  // ---- exclusive prefix scan of keepf (2 elems/thread, shfl wave scan + cross-wave)
  int a0 = keepf[2 * tid], a1 = keepf[2 * tid + 1];
  int ts = a0 + a1;
  int lane = tid & 63, wid = tid >> 6;
  int v = ts;
  for (int d = 1; d < 64; d <<= 1) {
    int u = __shfl_up(v, d, 64);
    if (lane >= d) v += u;
  }
  if (lane == 63) wsum[wid] = v;
  __syncthreads();
  if (tid < 16) {
    int w = wsum[tid];
    for (int d = 1; d < 16; d <<= 1) {
      int u = __shfl_up(w, d, 16);
      if (tid >= d) w += u;
    }
    wscan[tid] = w;
    if (tid == 15) Ktot = w;
  }
  __syncthreads();
  int base = (wid == 0 ? 0 : wscan[wid - 1]) + (v - ts);
  pexc[2 * tid] = base;
  pexc[2 * tid + 1] = base + a0;
  __syncthreads();

  for (int i = tid; i < NBOX; i += 1024)
    if (keepf[i]) plist[pexc[i]] = (unsigned short)i;
  __syncthreads();

  // ---- write every output element exactly once: rank r < K -> kept data, else zeros
  const int K = Ktot;
  for (int r = tid; r < NBOX; r += 1024) {
    float b0 = 0, b1 = 0, b2 = 0, b3 = 0, sc = 0, cp = 0, lbf = 0, mk = 0;
    if (r < K) {
      int i = plist[r];
      unsigned long long kv = key[i];
      unsigned meta = (unsigned)kv;
      int orig = (meta >> 7) & (NBOX - 1);
      int lb = meta & 127;
      const float* rr = det + (ibase + orig) * ROWF;   // ORIGINAL (non-offset) boxes
      b0 = rr[0]; b1 = rr[1]; b2 = rr[2]; b3 = rr[3];
      sc = __uint_as_float(~(unsigned)(kv >> 32));
      cp = cp_ws[ibase + orig];
      lbf = (float)lb;
      mk = 1.0f;
    }
    float* orow = out + (ibase + r) * 6;
    orow[0] = b0; orow[1] = b1; orow[2] = b2; orow[3] = b3; orow[4] = sc; orow[5] = cp;
    olb[ibase + r] = lbf;
    omask[ibase + r] = mk;
  }
}

extern "C" void kernel_launch(void* const* d_in, const int* in_sizes, int n_in,
                              void* d_out, int out_size, void* d_ws, size_t ws_size,
                              hipStream_t stream) {
  const float* det = (const float*)d_in[0];
  float* out = (float*)d_out;
  float* olb = out + (size_t)BATCH * NBOX * 6;
  float* omask = out + (size_t)BATCH * NBOX * 7;

  float* s_ws = (float*)d_ws;                 // B*N floats
  float* cp_ws = s_ws + BATCH * NBOX;         // B*N floats
  int* l_ws = (int*)(cp_ws + BATCH * NBOX);   // B*N ints   (total 384 KB of ws)

  prep_kernel<<<(BATCH * NBOX) / 256, 256, 0, stream>>>(det, s_ws, cp_ws, l_ws);
  nms_kernel<<<BATCH, 1024, 0, stream>>>(det, s_ws, cp_ws, l_ws, out, olb, omask);
}

// Round 2
// 218.542 us; speedup vs baseline: 13.2282x; 13.2282x over previous
//
#include <hip/hip_runtime.h>

#define BATCH 16
#define NBOX  2048
#define NCLS  80
#define ROWF  85          // 4 box + 1 score + 80 classprobs
#define CONF_THRF 0.2f
#define NMS_THRF  0.45f
#define CAP   256         // max candidates per (image,class); stats say ~25, 256 is paranoid-safe

// ---------------- kernel 1: per-box score / classprob max / argmax ----------------
__global__ __launch_bounds__(256) void prep_kernel(const float* __restrict__ det,
                                                   float* __restrict__ s_ws,
                                                   float* __restrict__ cp_ws,
                                                   int* __restrict__ l_ws) {
  int g = blockIdx.x * blockDim.x + threadIdx.x;
  if (g >= BATCH * NBOX) return;
  const float* r = det + (size_t)g * ROWF;
  float sc = r[4];
  float best = r[5];
  int bi = 0;
#pragma unroll
  for (int c = 1; c < NCLS; ++c) {
    float v = r[5 + c];
    if (v > best) { best = v; bi = c; }   // strict > keeps FIRST max (argmax semantics)
  }
  s_ws[g] = sc;
  cp_ws[g] = best;
  l_ws[g] = bi;
}

// ---------------- kernel 2: per-image sort + wave-parallel per-class NMS + compact ----------------
__global__ __launch_bounds__(1024) void nms_kernel(const float* __restrict__ det,
                                                   const float* __restrict__ s_ws,
                                                   const float* __restrict__ cp_ws,
                                                   const int* __restrict__ l_ws,
                                                   float* __restrict__ out,
                                                   float* __restrict__ olb,
                                                   float* __restrict__ omask) {
  __shared__ unsigned long long key[NBOX];                      // 16 KB
  __shared__ float bx1[NBOX], by1[NBOX], bx2[NBOX], by2[NBOX];  // 32 KB (offset boxes, sorted order)
  __shared__ unsigned short clist[NCLS][CAP];                   // 40 KB per-class candidate positions
  __shared__ int ccnt[NCLS];                                    // per-class candidate counts
  __shared__ unsigned char keepf[NBOX];                         // 2 KB
  __shared__ int pexc[NBOX];                                    // 8 KB exclusive prefix of keep
  __shared__ unsigned short plist[NBOX];                        // 4 KB rank -> sorted position
  __shared__ int wsum[16], wscan[16];
  __shared__ int Ktot;

  const int img = blockIdx.x;
  const int tid = threadIdx.x;
  const int lane = tid & 63, wid = tid >> 6;
  const size_t ibase = (size_t)img * NBOX;

  // ---- build sort keys: (~score_bits)<<32 | (idx<<7 | label); non-candidates -> hi=0xFFFFFFFF
  // ascending 64-bit sort == stable (score desc, idx asc), non-candidates last in idx order,
  // exactly matching jnp stable argsort of -where(cand, s, -inf).
  for (int i = tid; i < NBOX; i += 1024) {
    float sc = s_ws[ibase + i];
    int lb = l_ws[ibase + i];
    unsigned sb = __float_as_uint(sc);            // sc in [0,1): bits monotone with value
    unsigned hi = (sc > CONF_THRF) ? ~sb : 0xFFFFFFFFu;
    key[i] = ((unsigned long long)hi << 32) | (unsigned)((i << 7) | lb);
    keepf[i] = 0;
  }
  __syncthreads();

  // ---- bitonic sort ascending, 2048 elems, 1024 threads = 1 pair/thread/pass
  for (int k = 2; k <= NBOX; k <<= 1) {
    for (int j = k >> 1; j > 0; j >>= 1) {
      int i = ((tid & ~(j - 1)) << 1) | (tid & (j - 1));
      int ixj = i + j;
      unsigned long long a = key[i], b = key[ixj];
      bool up = ((i & k) == 0);
      if (up ? (a > b) : (a < b)) { key[i] = b; key[ixj] = a; }
      __syncthreads();
    }
  }

  // ---- gather offset boxes (b + label*10000, f32, same rounding as reference) in sorted order
  for (int i = tid; i < NBOX; i += 1024) {
    unsigned meta = (unsigned)key[i];
    int orig = (meta >> 7) & (NBOX - 1);
    int lb = meta & 127;
    const float* rr = det + (ibase + orig) * ROWF;
    float off = (float)lb * 10000.0f;
    bx1[i] = rr[0] + off;
    by1[i] = rr[1] + off;
    bx2[i] = rr[2] + off;
    by2[i] = rr[3] + off;
  }
  __syncthreads();

  // ---- per-class candidate lists (order-preserving 80-thread scan; cheap per iteration)
  if (tid < NCLS) {
    int c = tid, cnt = 0;
    for (int i = 0; i < NBOX; ++i) {
      unsigned long long kv = key[i];
      if ((unsigned)(kv >> 32) == 0xFFFFFFFFu) break;  // uniform across lanes (same kv)
      if (((unsigned)kv & 127u) == (unsigned)c) {
        if (cnt < CAP) clist[c][cnt] = (unsigned short)i;
        cnt++;
      }
    }
    ccnt[c] = cnt < CAP ? cnt : CAP;
  }
  __syncthreads();

  // ---- wave-parallel greedy NMS: wave w owns classes w, w+16, ... (5 each).
  // Classes never interact (label offset >= 10000 apart -> cross-class IoU == 0).
  for (int c = wid; c < NCLS; c += 16) {
    int m = ccnt[c];
    for (int base = 0; base < m; base += 64) {
      int q = base + lane;
      bool valid = q < m;
      int pos = valid ? clist[c][q] : 0;
      float x1 = bx1[pos], y1 = by1[pos], x2 = bx2[pos], y2 = by2[pos];
      float ar = fmaxf(x2 - x1, 0.0f) * fmaxf(y2 - y1, 0.0f);
      // suppress vs kept boxes from earlier chunks (rare: m > 64)
      bool dead = false;
      for (int t = 0; t < base; ++t) {
        int kp = clist[c][t];
        if (!keepf[kp]) continue;                      // uniform (broadcast read)
        float kx1 = bx1[kp], ky1 = by1[kp], kx2 = bx2[kp], ky2 = by2[kp];
        float kar = fmaxf(kx2 - kx1, 0.0f) * fmaxf(ky2 - ky1, 0.0f);
        float iw = fminf(x2, kx2) - fmaxf(x1, kx1);
        float ih = fminf(y2, ky2) - fmaxf(y1, ky1);
        float inter = fmaxf(iw, 0.0f) * fmaxf(ih, 0.0f);
        float iou = inter / (((kar + ar) - inter) + 1e-7f);
        dead |= (iou > NMS_THRF);
      }
      // intra-chunk iterative ballot-greedy
      unsigned long long und = __ballot(valid && !dead);
      while (und) {
        int i = __ffsll((long long)und) - 1;           // first undecided = kept
        int kpos = clist[c][base + i];                 // broadcast read
        if (lane == i) keepf[kpos] = 1;
        float kx1 = bx1[kpos], ky1 = by1[kpos], kx2 = bx2[kpos], ky2 = by2[kpos];
        float kar = fmaxf(kx2 - kx1, 0.0f) * fmaxf(ky2 - ky1, 0.0f);
        float iw = fminf(x2, kx2) - fmaxf(x1, kx1);
        float ih = fminf(y2, ky2) - fmaxf(y1, ky1);
        float inter = fmaxf(iw, 0.0f) * fmaxf(ih, 0.0f);
        float iou = inter / (((kar + ar) - inter) + 1e-7f);  // exact ref op order
        bool sup = (lane > i) && (iou > NMS_THRF);
        und &= ~__ballot(sup);
        und &= ~(1ull << i);
      }
    }
  }
  __syncthreads();

  // ---- exclusive prefix scan of keepf (2 elems/thread, shfl wave scan + cross-wave)
  int a0 = keepf[2 * tid], a1 = keepf[2 * tid + 1];
  int ts = a0 + a1;
  int v = ts;
  for (int d = 1; d < 64; d <<= 1) {
    int u = __shfl_up(v, d, 64);
    if (lane >= d) v += u;
  }
  if (lane == 63) wsum[wid] = v;
  __syncthreads();
  if (tid < 16) {
    int w = wsum[tid];
    for (int d = 1; d < 16; d <<= 1) {
      int u = __shfl_up(w, d, 16);
      if (tid >= d) w += u;
    }
    wscan[tid] = w;
    if (tid == 15) Ktot = w;
  }
  __syncthreads();
  int sbase = (wid == 0 ? 0 : wscan[wid - 1]) + (v - ts);
  pexc[2 * tid] = sbase;
  pexc[2 * tid + 1] = sbase + a0;
  __syncthreads();

  for (int i = tid; i < NBOX; i += 1024)
    if (keepf[i]) plist[pexc[i]] = (unsigned short)i;
  __syncthreads();

  // ---- write every output element exactly once: rank r < K -> kept data, else zeros
  const int K = Ktot;
  for (int r = tid; r < NBOX; r += 1024) {
    float b0 = 0, b1 = 0, b2 = 0, b3 = 0, sc = 0, cp = 0, lbf = 0, mk = 0;
    if (r < K) {
      int i = plist[r];
      unsigned long long kv = key[i];
      unsigned meta = (unsigned)kv;
      int orig = (meta >> 7) & (NBOX - 1);
      int lb = meta & 127;
      const float* rr = det + (ibase + orig) * ROWF;   // ORIGINAL (non-offset) boxes
      b0 = rr[0]; b1 = rr[1]; b2 = rr[2]; b3 = rr[3];
      sc = __uint_as_float(~(unsigned)(kv >> 32));
      cp = cp_ws[ibase + orig];
      lbf = (float)lb;
      mk = 1.0f;
    }
    float* orow = out + (ibase + r) * 6;
    orow[0] = b0; orow[1] = b1; orow[2] = b2; orow[3] = b3; orow[4] = sc; orow[5] = cp;
    olb[ibase + r] = lbf;
    omask[ibase + r] = mk;
  }
}

extern "C" void kernel_launch(void* const* d_in, const int* in_sizes, int n_in,
                              void* d_out, int out_size, void* d_ws, size_t ws_size,
                              hipStream_t stream) {
  const float* det = (const float*)d_in[0];
  float* out = (float*)d_out;
  float* olb = out + (size_t)BATCH * NBOX * 6;
  float* omask = out + (size_t)BATCH * NBOX * 7;

  float* s_ws = (float*)d_ws;                 // B*N floats
  float* cp_ws = s_ws + BATCH * NBOX;         // B*N floats
  int* l_ws = (int*)(cp_ws + BATCH * NBOX);   // B*N ints   (total 384 KB of ws)

  prep_kernel<<<(BATCH * NBOX) / 256, 256, 0, stream>>>(det, s_ws, cp_ws, l_ws);
  nms_kernel<<<BATCH, 1024, 0, stream>>>(det, s_ws, cp_ws, l_ws, out, olb, omask);
}

// Round 3
// 77.556 us; speedup vs baseline: 37.2752x; 2.8179x over previous
//
#include <hip/hip_runtime.h>

#define BATCH 16
#define NBOX  2048
#define NCLS  80
#define ROWF  85          // 4 box + 1 score + 80 classprobs
#define CONF_THRF 0.2f
#define NMS_THRF  0.45f
#define CAP   256         // max candidates per (image,class); stats say ~21 avg, 256 is paranoid-safe

// ---------------- kernel 1: per-box score / classprob max / argmax ----------------
__global__ __launch_bounds__(256) void prep_kernel(const float* __restrict__ det,
                                                   float* __restrict__ s_ws,
                                                   float* __restrict__ cp_ws,
                                                   int* __restrict__ l_ws) {
  int g = blockIdx.x * blockDim.x + threadIdx.x;
  if (g >= BATCH * NBOX) return;
  const float* r = det + (size_t)g * ROWF;
  float sc = r[4];
  float best = r[5];
  int bi = 0;
#pragma unroll
  for (int c = 1; c < NCLS; ++c) {
    float v = r[5 + c];
    if (v > best) { best = v; bi = c; }   // strict > keeps FIRST max (argmax semantics)
  }
  s_ws[g] = sc;
  cp_ws[g] = best;
  l_ws[g] = bi;
}

// ---------------- kernel 2: per-image sort + wave-parallel per-class NMS + compact ----------------
__global__ __launch_bounds__(1024) void nms_kernel(const float* __restrict__ det,
                                                   const float* __restrict__ s_ws,
                                                   const float* __restrict__ cp_ws,
                                                   const int* __restrict__ l_ws,
                                                   float* __restrict__ out,
                                                   float* __restrict__ olb,
                                                   float* __restrict__ omask) {
  __shared__ unsigned long long key[NBOX];                      // 16 KB
  __shared__ float bx1[NBOX], by1[NBOX], bx2[NBOX], by2[NBOX];  // 32 KB (offset boxes, sorted order)
  __shared__ unsigned short clist[NCLS][CAP];                   // 40 KB per-class candidate positions
  __shared__ unsigned short hist[32][NCLS];                     // 5 KB per-chunk class histogram -> prefix
  __shared__ int ccnt[NCLS];                                    // per-class candidate counts
  __shared__ unsigned char keepf[NBOX];                         // 2 KB
  __shared__ int pexc[NBOX];                                    // 8 KB exclusive prefix of keep
  __shared__ unsigned short plist[NBOX];                        // 4 KB rank -> sorted position
  __shared__ int wsum[16], wscan[16];
  __shared__ int Ktot;

  const int img = blockIdx.x;
  const int tid = threadIdx.x;
  const int lane = tid & 63, wid = tid >> 6;
  const size_t ibase = (size_t)img * NBOX;

  // ---- build sort keys: (~score_bits)<<32 | (idx<<7 | label); non-candidates -> hi=0xFFFFFFFF
  // ascending 64-bit sort == stable (score desc, idx asc), non-candidates last in idx order,
  // exactly matching jnp stable argsort of -where(cand, s, -inf).
  for (int i = tid; i < NBOX; i += 1024) {
    float sc = s_ws[ibase + i];
    int lb = l_ws[ibase + i];
    unsigned sb = __float_as_uint(sc);            // sc in [0,1): bits monotone with value
    unsigned hi = (sc > CONF_THRF) ? ~sb : 0xFFFFFFFFu;
    key[i] = ((unsigned long long)hi << 32) | (unsigned)((i << 7) | lb);
    keepf[i] = 0;
  }
  __syncthreads();

  // ---- bitonic sort ascending, 2048 elems, 1024 threads = 1 pair/thread/pass
  for (int k = 2; k <= NBOX; k <<= 1) {
    for (int j = k >> 1; j > 0; j >>= 1) {
      int i = ((tid & ~(j - 1)) << 1) | (tid & (j - 1));
      int ixj = i + j;
      unsigned long long a = key[i], b = key[ixj];
      bool up = ((i & k) == 0);
      if (up ? (a > b) : (a < b)) { key[i] = b; key[ixj] = a; }
      __syncthreads();
    }
  }

  // ---- gather offset boxes (b + label*10000, f32, same rounding as reference) in sorted order
  for (int i = tid; i < NBOX; i += 1024) {
    unsigned meta = (unsigned)key[i];
    int orig = (meta >> 7) & (NBOX - 1);
    int lb = meta & 127;
    const float* rr = det + (ibase + orig) * ROWF;
    float off = (float)lb * 10000.0f;
    bx1[i] = rr[0] + off;
    by1[i] = rr[1] + off;
    bx2[i] = rr[2] + off;
    by2[i] = rr[3] + off;
  }
  // no barrier needed yet: phase 1 below only reads key[] (already barriered after sort)

  // ---- per-class candidate lists via parallel ballot-histogram rank (3 phases) ----
  // phase 1: per 64-elem chunk, one ballot per class gives chunk count + within-chunk rank
  int lrank[2], cls[2];
#pragma unroll
  for (int cc = 0; cc < 2; ++cc) {
    int ch = 2 * wid + cc;
    int i = ch * 64 + lane;
    unsigned long long kv = key[i];
    int c = (((unsigned)(kv >> 32)) != 0xFFFFFFFFu) ? (int)((unsigned)kv & 127u) : 255;
    cls[cc] = c;
    lrank[cc] = 0;
    for (int cq = 0; cq < NCLS; ++cq) {
      unsigned long long mask = __ballot(c == cq);
      if (c == cq) lrank[cc] = __popcll(mask & ((1ull << lane) - 1ull));
      if (lane == (cq & 63)) hist[ch][cq] = (unsigned short)__popcll(mask);
    }
  }
  __syncthreads();
  // phase 2: exclusive prefix over chunks per class (80 threads, 32 steps)
  if (tid < NCLS) {
    int run = 0;
    for (int k = 0; k < 32; ++k) {
      int t = hist[k][tid];
      hist[k][tid] = (unsigned short)run;
      run += t;
    }
    ccnt[tid] = run;
  }
  __syncthreads();
  // phase 3: scatter each candidate to its class list at global rank (order-preserving)
#pragma unroll
  for (int cc = 0; cc < 2; ++cc) {
    int c = cls[cc];
    if (c < NCLS) {
      int ch = 2 * wid + cc;
      int rank = (int)hist[ch][c] + lrank[cc];
      if (rank < CAP) clist[c][rank] = (unsigned short)(ch * 64 + lane);
    }
  }
  __syncthreads();

  // ---- wave-parallel greedy NMS: wave w owns classes w, w+16, ... (5 each).
  // Classes never interact (label offset >= 10000 apart -> cross-class IoU == 0).
  for (int c = wid; c < NCLS; c += 16) {
    int m = ccnt[c] < CAP ? ccnt[c] : CAP;
    for (int base = 0; base < m; base += 64) {
      int q = base + lane;
      bool valid = q < m;
      int qc = valid ? q : 0;
      int pos = clist[c][qc];
      float x1 = bx1[pos], y1 = by1[pos], x2 = bx2[pos], y2 = by2[pos];
      float ar = fmaxf(x2 - x1, 0.0f) * fmaxf(y2 - y1, 0.0f);
      // suppress vs kept boxes from earlier chunks (rare: m > 64)
      bool dead = false;
      for (int t = 0; t < base; ++t) {
        int kp = clist[c][t];
        if (!keepf[kp]) continue;                      // uniform (broadcast read)
        float kx1 = bx1[kp], ky1 = by1[kp], kx2 = bx2[kp], ky2 = by2[kp];
        float kar = fmaxf(kx2 - kx1, 0.0f) * fmaxf(ky2 - ky1, 0.0f);
        float iw = fminf(x2, kx2) - fmaxf(x1, kx1);
        float ih = fminf(y2, ky2) - fmaxf(y1, ky1);
        float inter = fmaxf(iw, 0.0f) * fmaxf(ih, 0.0f);
        float iou = inter / (((kar + ar) - inter) + 1e-7f);
        dead |= (iou > NMS_THRF);
      }
      // intra-chunk iterative ballot-greedy; kept box broadcast via shfl (register-resident)
      unsigned long long und = __ballot(valid && !dead);
      while (und) {
        int i = __ffsll((long long)und) - 1;           // first undecided = kept
        float kx1 = __shfl(x1, i, 64), ky1 = __shfl(y1, i, 64);
        float kx2 = __shfl(x2, i, 64), ky2 = __shfl(y2, i, 64);
        float kar = __shfl(ar, i, 64);
        if (lane == i) keepf[pos] = 1;
        float iw = fminf(x2, kx2) - fmaxf(x1, kx1);
        float ih = fminf(y2, ky2) - fmaxf(y1, ky1);
        float inter = fmaxf(iw, 0.0f) * fmaxf(ih, 0.0f);
        float iou = inter / (((kar + ar) - inter) + 1e-7f);  // exact ref op order
        bool sup = (lane > i) && (iou > NMS_THRF);
        und &= ~__ballot(sup);
        und &= ~(1ull << i);
      }
    }
  }
  __syncthreads();

  // ---- exclusive prefix scan of keepf (2 elems/thread, shfl wave scan + cross-wave)
  int a0 = keepf[2 * tid], a1 = keepf[2 * tid + 1];
  int ts = a0 + a1;
  int v = ts;
  for (int d = 1; d < 64; d <<= 1) {
    int u = __shfl_up(v, d, 64);
    if (lane >= d) v += u;
  }
  if (lane == 63) wsum[wid] = v;
  __syncthreads();
  if (tid < 16) {
    int w = wsum[tid];
    for (int d = 1; d < 16; d <<= 1) {
      int u = __shfl_up(w, d, 16);
      if (tid >= d) w += u;
    }
    wscan[tid] = w;
    if (tid == 15) Ktot = w;
  }
  __syncthreads();
  int sbase = (wid == 0 ? 0 : wscan[wid - 1]) + (v - ts);
  pexc[2 * tid] = sbase;
  pexc[2 * tid + 1] = sbase + a0;
  __syncthreads();

  for (int i = tid; i < NBOX; i += 1024)
    if (keepf[i]) plist[pexc[i]] = (unsigned short)i;
  __syncthreads();

  // ---- write every output element exactly once: rank r < K -> kept data, else zeros
  const int K = Ktot;
  for (int r = tid; r < NBOX; r += 1024) {
    float b0 = 0, b1 = 0, b2 = 0, b3 = 0, sc = 0, cp = 0, lbf = 0, mk = 0;
    if (r < K) {
      int i = plist[r];
      unsigned long long kv = key[i];
      unsigned meta = (unsigned)kv;
      int orig = (meta >> 7) & (NBOX - 1);
      int lb = meta & 127;
      const float* rr = det + (ibase + orig) * ROWF;   // ORIGINAL (non-offset) boxes
      b0 = rr[0]; b1 = rr[1]; b2 = rr[2]; b3 = rr[3];
      sc = __uint_as_float(~(unsigned)(kv >> 32));
      cp = cp_ws[ibase + orig];
      lbf = (float)lb;
      mk = 1.0f;
    }
    float* orow = out + (ibase + r) * 6;
    orow[0] = b0; orow[1] = b1; orow[2] = b2; orow[3] = b3; orow[4] = sc; orow[5] = cp;
    olb[ibase + r] = lbf;
    omask[ibase + r] = mk;
  }
}

extern "C" void kernel_launch(void* const* d_in, const int* in_sizes, int n_in,
                              void* d_out, int out_size, void* d_ws, size_t ws_size,
                              hipStream_t stream) {
  const float* det = (const float*)d_in[0];
  float* out = (float*)d_out;
  float* olb = out + (size_t)BATCH * NBOX * 6;
  float* omask = out + (size_t)BATCH * NBOX * 7;

  float* s_ws = (float*)d_ws;                 // B*N floats
  float* cp_ws = s_ws + BATCH * NBOX;         // B*N floats
  int* l_ws = (int*)(cp_ws + BATCH * NBOX);   // B*N ints   (total 384 KB of ws)

  prep_kernel<<<(BATCH * NBOX) / 256, 256, 0, stream>>>(det, s_ws, cp_ws, l_ws);
  nms_kernel<<<BATCH, 1024, 0, stream>>>(det, s_ws, cp_ws, l_ws, out, olb, omask);
}

// Round 4
// 74.331 us; speedup vs baseline: 38.8924x; 1.0434x over previous
//
#include <hip/hip_runtime.h>

#define BATCH 16
#define NBOX  2048
#define NCLS  80
#define ROWF  85          // 4 box + 1 score + 80 classprobs
#define CONF_THRF 0.2f
#define NMS_THRF  0.45f
#define CAP   256         // max candidates per (image,class); stats say ~21 avg, 256 is paranoid-safe

// ---------------- kernel 1: per-box score / classprob max / argmax (one wave per row) ------------
__global__ __launch_bounds__(256) void prep_kernel(const float* __restrict__ det,
                                                   float* __restrict__ s_ws,
                                                   float* __restrict__ cp_ws,
                                                   int* __restrict__ l_ws) {
  int gw = (blockIdx.x * blockDim.x + threadIdx.x) >> 6;   // global wave id == row id
  int lane = threadIdx.x & 63;
  if (gw >= BATCH * NBOX) return;
  const float* r = det + (size_t)gw * ROWF;
  float v = r[5 + lane];                                   // coalesced: 64 lanes x 4B
  int idx = lane;
  if (lane < NCLS - 64) {                                  // lanes 0..15 also cover c=64..79
    float v2 = r[5 + 64 + lane];
    if (v2 > v) { v = v2; idx = 64 + lane; }               // strict >: lower idx wins ties
  }
  // wave argmax reduce; first-max semantics: max val, tie -> min idx
  for (int d = 32; d > 0; d >>= 1) {
    float ov = __shfl_down(v, d, 64);
    int oi = __shfl_down(idx, d, 64);
    if (ov > v || (ov == v && oi < idx)) { v = ov; idx = oi; }
  }
  if (lane == 0) { s_ws[gw] = r[4]; cp_ws[gw] = v; l_ws[gw] = idx; }
}

static __device__ inline unsigned long long shflx64(unsigned long long v, int m) {
  int lo = __shfl_xor((int)(unsigned)(v & 0xffffffffull), m, 64);
  int hi = __shfl_xor((int)(unsigned)(v >> 32), m, 64);
  return ((unsigned long long)(unsigned)hi << 32) | (unsigned)lo;
}

// ---------------- kernel 2: per-image reg-bitonic sort + wave-parallel NMS + compact -------------
__global__ __launch_bounds__(1024) void nms_kernel(const float* __restrict__ det,
                                                   const float* __restrict__ s_ws,
                                                   const float* __restrict__ cp_ws,
                                                   const int* __restrict__ l_ws,
                                                   float* __restrict__ out,
                                                   float* __restrict__ olb,
                                                   float* __restrict__ omask) {
  __shared__ unsigned long long key[NBOX];                      // 16 KB
  __shared__ float bx1[NBOX], by1[NBOX], bx2[NBOX], by2[NBOX];  // 32 KB (offset boxes, sorted order)
  __shared__ unsigned short clist[NCLS][CAP];                   // 40 KB per-class candidate positions
  __shared__ unsigned short hist[32][NCLS];                     // 5 KB per-chunk class histogram -> prefix
  __shared__ int ccnt[NCLS];
  __shared__ unsigned char keepf[NBOX];                         // 2 KB
  __shared__ int pexc[NBOX];                                    // 8 KB exclusive prefix of keep
  __shared__ unsigned short plist[NBOX];                        // 4 KB rank -> sorted position
  __shared__ int wsum[16], wscan[16];
  __shared__ int Ktot;

  const int img = blockIdx.x;
  const int tid = threadIdx.x;
  const int lane = tid & 63, wid = tid >> 6;
  const size_t ibase = (size_t)img * NBOX;
  const int i0 = (wid << 7) + lane;                             // this thread owns elems i0, i0+64
  const int i1 = i0 + 64;

  // ---- build sort keys DIRECTLY IN REGISTERS: (~score_bits)<<32 | (idx<<7 | label)
  // ascending 64-bit sort == stable (score desc, idx asc), non-candidates (hi=0xFFFFFFFF) last
  // in idx order — exactly matching jnp stable argsort of -where(cand, s, -inf).
  unsigned long long e0, e1;
  {
    float sc0 = s_ws[ibase + i0], sc1 = s_ws[ibase + i1];
    int lb0 = l_ws[ibase + i0], lb1 = l_ws[ibase + i1];
    unsigned hi0 = (sc0 > CONF_THRF) ? ~__float_as_uint(sc0) : 0xFFFFFFFFu;
    unsigned hi1 = (sc1 > CONF_THRF) ? ~__float_as_uint(sc1) : 0xFFFFFFFFu;
    e0 = ((unsigned long long)hi0 << 32) | (unsigned)((i0 << 7) | lb0);
    e1 = ((unsigned long long)hi1 << 32) | (unsigned)((i1 << 7) | lb1);
  }
  keepf[2 * tid] = 0; keepf[2 * tid + 1] = 0;

  // ---- bitonic stages k=2..128: fully in-register (shfl_xor; j==64 is in-lane). No barriers.
#pragma unroll
  for (int k = 2; k <= 128; k <<= 1) {
    for (int j = k >> 1; j > 0; j >>= 1) {
      if (j == 64) {
        bool up = ((i0 & k) == 0);
        if (up ? (e0 > e1) : (e0 < e1)) { unsigned long long t = e0; e0 = e1; e1 = t; }
      } else {
        bool amLow = (lane & j) == 0;
        bool up0 = ((i0 & k) == 0), up1 = ((i1 & k) == 0);
        unsigned long long o0 = shflx64(e0, j), o1 = shflx64(e1, j);
        e0 = (up0 == amLow) ? (e0 < o0 ? e0 : o0) : (e0 > o0 ? e0 : o0);
        e1 = (up1 == amLow) ? (e1 < o1 ? e1 : o1) : (e1 > o1 ? e1 : o1);
      }
    }
  }

  // ---- stages k=256..2048: j>=128 via LDS, j<=64 back in registers
  for (int k = 256; k <= NBOX; k <<= 1) {
    key[i0] = e0; key[i1] = e1;
    __syncthreads();
    for (int j = k >> 1; j >= 128; j >>= 1) {
      int i = ((tid & ~(j - 1)) << 1) | (tid & (j - 1));
      int ixj = i + j;
      unsigned long long a = key[i], b = key[ixj];
      bool up = ((i & k) == 0);
      if (up ? (a > b) : (a < b)) { key[i] = b; key[ixj] = a; }
      __syncthreads();
    }
    e0 = key[i0]; e1 = key[i1];       // own slots only; safe post-barrier
#pragma unroll
    for (int j = 64; j > 0; j >>= 1) {
      if (j == 64) {
        bool up = ((i0 & k) == 0);
        if (up ? (e0 > e1) : (e0 < e1)) { unsigned long long t = e0; e0 = e1; e1 = t; }
      } else {
        bool amLow = (lane & j) == 0;
        bool up0 = ((i0 & k) == 0), up1 = ((i1 & k) == 0);
        unsigned long long o0 = shflx64(e0, j), o1 = shflx64(e1, j);
        e0 = (up0 == amLow) ? (e0 < o0 ? e0 : o0) : (e0 > o0 ? e0 : o0);
        e1 = (up1 == amLow) ? (e1 < o1 ? e1 : o1) : (e1 > o1 ? e1 : o1);
      }
    }
  }
  key[i0] = e0; key[i1] = e1;          // final sorted array to LDS (needed by output phase)

  // ---- gather offset boxes (b + label*10000, f32, same rounding as ref) straight from regs
  {
    unsigned meta0 = (unsigned)e0, meta1 = (unsigned)e1;
    int og0 = (meta0 >> 7) & (NBOX - 1), og1 = (meta1 >> 7) & (NBOX - 1);
    float of0 = (float)(meta0 & 127) * 10000.0f, of1 = (float)(meta1 & 127) * 10000.0f;
    const float* r0 = det + (ibase + og0) * ROWF;
    const float* r1 = det + (ibase + og1) * ROWF;
    bx1[i0] = r0[0] + of0; by1[i0] = r0[1] + of0; bx2[i0] = r0[2] + of0; by2[i0] = r0[3] + of0;
    bx1[i1] = r1[0] + of1; by1[i1] = r1[1] + of1; bx2[i1] = r1[2] + of1; by2[i1] = r1[3] + of1;
  }

  // ---- per-class candidate lists via parallel ballot-histogram rank (regs, 3 phases) ----
  int c0 = (((unsigned)(e0 >> 32)) != 0xFFFFFFFFu) ? (int)((unsigned)e0 & 127u) : 255;
  int c1 = (((unsigned)(e1 >> 32)) != 0xFFFFFFFFu) ? (int)((unsigned)e1 & 127u) : 255;
  int lr0 = 0, lr1 = 0;
  for (int cq = 0; cq < NCLS; ++cq) {
    unsigned long long m0 = __ballot(c0 == cq);
    unsigned long long m1 = __ballot(c1 == cq);
    if (c0 == cq) lr0 = __popcll(m0 & ((1ull << lane) - 1ull));
    if (c1 == cq) lr1 = __popcll(m1 & ((1ull << lane) - 1ull));
    if (lane == (cq & 63)) {
      hist[2 * wid][cq] = (unsigned short)__popcll(m0);
      hist[2 * wid + 1][cq] = (unsigned short)__popcll(m1);
    }
  }
  __syncthreads();
  if (tid < NCLS) {                    // exclusive prefix over 32 chunks per class
    int run = 0;
    for (int k = 0; k < 32; ++k) {
      int t = hist[k][tid];
      hist[k][tid] = (unsigned short)run;
      run += t;
    }
    ccnt[tid] = run;
  }
  __syncthreads();
  if (c0 < NCLS) {
    int rank = (int)hist[2 * wid][c0] + lr0;
    if (rank < CAP) clist[c0][rank] = (unsigned short)i0;
  }
  if (c1 < NCLS) {
    int rank = (int)hist[2 * wid + 1][c1] + lr1;
    if (rank < CAP) clist[c1][rank] = (unsigned short)i1;
  }
  __syncthreads();

  // ---- wave-parallel greedy NMS: wave w owns classes w, w+16, ... (5 each).
  // Classes never interact (label offset >= 10000 apart -> cross-class IoU == 0).
  for (int c = wid; c < NCLS; c += 16) {
    int m = ccnt[c] < CAP ? ccnt[c] : CAP;
    for (int base = 0; base < m; base += 64) {
      int q = base + lane;
      bool valid = q < m;
      int qc = valid ? q : 0;
      int pos = clist[c][qc];
      float x1 = bx1[pos], y1 = by1[pos], x2 = bx2[pos], y2 = by2[pos];
      float ar = fmaxf(x2 - x1, 0.0f) * fmaxf(y2 - y1, 0.0f);
      bool dead = false;
      for (int t = 0; t < base; ++t) {               // rare: m > 64
        int kp = clist[c][t];
        if (!keepf[kp]) continue;
        float kx1 = bx1[kp], ky1 = by1[kp], kx2 = bx2[kp], ky2 = by2[kp];
        float kar = fmaxf(kx2 - kx1, 0.0f) * fmaxf(ky2 - ky1, 0.0f);
        float iw = fminf(x2, kx2) - fmaxf(x1, kx1);
        float ih = fminf(y2, ky2) - fmaxf(y1, ky1);
        float inter = fmaxf(iw, 0.0f) * fmaxf(ih, 0.0f);
        float iou = inter / (((kar + ar) - inter) + 1e-7f);
        dead |= (iou > NMS_THRF);
      }
      unsigned long long und = __ballot(valid && !dead);
      while (und) {
        int i = __ffsll((long long)und) - 1;         // first undecided = kept
        float kx1 = __shfl(x1, i, 64), ky1 = __shfl(y1, i, 64);
        float kx2 = __shfl(x2, i, 64), ky2 = __shfl(y2, i, 64);
        float kar = __shfl(ar, i, 64);
        if (lane == i) keepf[pos] = 1;
        float iw = fminf(x2, kx2) - fmaxf(x1, kx1);
        float ih = fminf(y2, ky2) - fmaxf(y1, ky1);
        float inter = fmaxf(iw, 0.0f) * fmaxf(ih, 0.0f);
        float iou = inter / (((kar + ar) - inter) + 1e-7f);  // exact ref op order
        bool sup = (lane > i) && (iou > NMS_THRF);
        und &= ~__ballot(sup);
        und &= ~(1ull << i);
      }
    }
  }
  __syncthreads();

  // ---- exclusive prefix scan of keepf (2 elems/thread, shfl wave scan + cross-wave)
  int a0 = keepf[2 * tid], a1 = keepf[2 * tid + 1];
  int ts = a0 + a1;
  int v = ts;
  for (int d = 1; d < 64; d <<= 1) {
    int u = __shfl_up(v, d, 64);
    if (lane >= d) v += u;
  }
  if (lane == 63) wsum[wid] = v;
  __syncthreads();
  if (tid < 16) {
    int w = wsum[tid];
    for (int d = 1; d < 16; d <<= 1) {
      int u = __shfl_up(w, d, 16);
      if (tid >= d) w += u;
    }
    wscan[tid] = w;
    if (tid == 15) Ktot = w;
  }
  __syncthreads();
  int sbase = (wid == 0 ? 0 : wscan[wid - 1]) + (v - ts);
  pexc[2 * tid] = sbase;
  pexc[2 * tid + 1] = sbase + a0;
  __syncthreads();

  for (int i = tid; i < NBOX; i += 1024)
    if (keepf[i]) plist[pexc[i]] = (unsigned short)i;
  __syncthreads();

  // ---- write every output element exactly once: rank r < K -> kept data, else zeros
  const int K = Ktot;
  for (int r = tid; r < NBOX; r += 1024) {
    float b0 = 0, b1 = 0, b2 = 0, b3 = 0, sc = 0, cp = 0, lbf = 0, mk = 0;
    if (r < K) {
      int i = plist[r];
      unsigned long long kv = key[i];
      unsigned meta = (unsigned)kv;
      int orig = (meta >> 7) & (NBOX - 1);
      int lb = meta & 127;
      const float* rr = det + (ibase + orig) * ROWF;   // ORIGINAL (non-offset) boxes
      b0 = rr[0]; b1 = rr[1]; b2 = rr[2]; b3 = rr[3];
      sc = __uint_as_float(~(unsigned)(kv >> 32));
      cp = cp_ws[ibase + orig];
      lbf = (float)lb;
      mk = 1.0f;
    }
    float* orow = out + (ibase + r) * 6;
    orow[0] = b0; orow[1] = b1; orow[2] = b2; orow[3] = b3; orow[4] = sc; orow[5] = cp;
    olb[ibase + r] = lbf;
    omask[ibase + r] = mk;
  }
}

extern "C" void kernel_launch(void* const* d_in, const int* in_sizes, int n_in,
                              void* d_out, int out_size, void* d_ws, size_t ws_size,
                              hipStream_t stream) {
  const float* det = (const float*)d_in[0];
  float* out = (float*)d_out;
  float* olb = out + (size_t)BATCH * NBOX * 6;
  float* omask = out + (size_t)BATCH * NBOX * 7;

  float* s_ws = (float*)d_ws;                 // B*N floats
  float* cp_ws = s_ws + BATCH * NBOX;         // B*N floats
  int* l_ws = (int*)(cp_ws + BATCH * NBOX);   // B*N ints   (total 384 KB of ws)

  prep_kernel<<<(BATCH * NBOX * 64) / 256, 256, 0, stream>>>(det, s_ws, cp_ws, l_ws);
  nms_kernel<<<BATCH, 1024, 0, stream>>>(det, s_ws, cp_ws, l_ws, out, olb, omask);
}